// Round 10
// baseline (165.116 us; speedup 1.0000x reference)
//
#include <hip/hip_runtime.h>
#include <hip/hip_bf16.h>

typedef __bf16 v8bf __attribute__((ext_vector_type(8)));
typedef float f32x4 __attribute__((ext_vector_type(4)));

__device__ __forceinline__ float bf2f(ushort u) {
    union { uint i; float f; } c; c.i = ((uint)u) << 16; return c.f;
}
__device__ __forceinline__ ushort f2bf(float f) {
    union { float f; uint i; } c; c.f = f;
    uint r = c.i + 0x7fffu + ((c.i >> 16) & 1u);
    return (ushort)(r >> 16);
}

// global -> LDS direct DMA, 16B per lane. LDS dest wave-uniform base; HW
// writes base + lane*16. Global src per-lane.
__device__ __forceinline__ void gld16(const ushort* g, ushort* l) {
    __builtin_amdgcn_global_load_lds(
        (const __attribute__((address_space(1))) uint*)(uintptr_t)g,
        (__attribute__((address_space(3))) uint*)(uint)(uintptr_t)l,
        16, 0, 0);
}

// ---------------------------------------------------------------------------
// fp32 -> bf16 conversion (weights)
// ---------------------------------------------------------------------------
__global__ __launch_bounds__(256)
void cvt_bf16_kernel(const float* __restrict__ src, ushort* __restrict__ dst, long n)
{
    long i = ((long)blockIdx.x * blockDim.x + threadIdx.x) * 8;
    if (i >= n) return;
    float4 a0 = *(const float4*)&src[i];
    float4 a1 = *(const float4*)&src[i + 4];
    ushort4 o0, o1;
    o0.x = f2bf(a0.x); o0.y = f2bf(a0.y); o0.z = f2bf(a0.z); o0.w = f2bf(a0.w);
    o1.x = f2bf(a1.x); o1.y = f2bf(a1.y); o1.z = f2bf(a1.z); o1.w = f2bf(a1.w);
    *(ushort4*)&dst[i]     = o0;
    *(ushort4*)&dst[i + 4] = o1;
}

// ---------------------------------------------------------------------------
// meas = cos(x + theta_attn[i & 63])   (fp32 in, bf16 out)
// ---------------------------------------------------------------------------
__global__ __launch_bounds__(256)
void meas_kernel(const float* __restrict__ x, const float* __restrict__ theta,
                 ushort* __restrict__ meas, long n)
{
    long i = ((long)blockIdx.x * blockDim.x + threadIdx.x) * 8;
    if (i >= n) return;
    float4 a0 = *(const float4*)&x[i];
    float4 a1 = *(const float4*)&x[i + 4];
    int tb = (int)(i & 63);
    float4 t0 = *(const float4*)&theta[tb];
    float4 t1 = *(const float4*)&theta[tb + 4];
    ushort4 o0, o1;
    o0.x = f2bf(cosf(a0.x + t0.x));
    o0.y = f2bf(cosf(a0.y + t0.y));
    o0.z = f2bf(cosf(a0.z + t0.z));
    o0.w = f2bf(cosf(a0.w + t0.w));
    o1.x = f2bf(cosf(a1.x + t1.x));
    o1.y = f2bf(cosf(a1.y + t1.y));
    o1.z = f2bf(cosf(a1.z + t1.z));
    o1.w = f2bf(cosf(a1.w + t1.w));
    *(ushort4*)&meas[i]     = o0;
    *(ushort4*)&meas[i + 4] = o1;
}

// ---------------------------------------------------------------------------
// Phase-interleaved pipelined GEMM: C = A @ B^T.
// BM=256 x BN=128, BK=64, 512 thr / 8 waves (2M x 4N, wave C = 128x32).
// Ring of 3 LDS slots (144 KB, 1 block/CU). Per K-tile: 4 phases
// {ds_read ∥ stage-issue → barrier → 8 MFMA (setprio) → barrier}, with the
// tile's FINAL barrier preceded by the counted vmcnt so the next tile's
// DMA is landed for ALL waves before anyone reads it (r9 race fix).
// Both-sides XOR swizzle chunk^=(row&7) (0 conflicts). T1 XCD swizzle.
// Requires K%64==0, K/64>=2, M%256==0, N%128==0, nwg%8==0.
// ---------------------------------------------------------------------------
__global__ __launch_bounds__(512)
void gemm_pipe8(const ushort* __restrict__ A, const ushort* __restrict__ B,
                ushort* __restrict__ C, int M, int N, int K)
{
    // slot: A [256 rows][64] at 0, B [128 rows][64] at 16384 (ushort idx)
    __shared__ ushort lds[3][24576];   // 3 x 48 KB = 144 KB

    const int t    = threadIdx.x;
    const int lane = t & 63;
    const int wid  = t >> 6;
    const int wm   = wid >> 2;     // 0..1 -> 128-row band
    const int wn   = wid & 3;      // 0..3 -> 32-col band

    int wg = blockIdx.y * gridDim.x + blockIdx.x;
    const int nwg = gridDim.x * gridDim.y;
    const int chunk = nwg >> 3;
    wg = (wg & 7) * chunk + (wg >> 3);
    const int bx = wg % gridDim.x;
    const int by = wg / gridDim.x;
    const long brow = (long)by * 256;
    const long bcol = (long)bx * 128;

    // staging: gld16 writes LDS linearly (lane -> row lane>>3, chunk lane&7).
    // Inverse swizzle on SOURCE so swizzled reads find chunk c at slot c^(r&7):
    const int lr = lane >> 3;                 // row within 8-row group
    const int co = ((lane & 7) ^ lr) * 8;     // global k-chunk (elems)
    const ushort* pa = A + (brow + wid * 32 + lr) * (long)K + co;
    const ushort* pb = B + (bcol + wid * 16 + lr) * (long)K + co;

    f32x4 acc[8][2];
    const f32x4 z = {0.f, 0.f, 0.f, 0.f};
    #pragma unroll
    for (int m = 0; m < 8; m++)
        for (int n = 0; n < 2; n++) acc[m][n] = z;

    const int fr = lane & 15;
    const int hi = lane >> 4;

    // stage-issue subsets for tile s (6 gld16/thread per tile total)
    auto stA01 = [&](int s) { int sl = s % 3; long k0 = (long)s * 64;
        gld16(pa + k0,           &lds[sl][(wid * 32 + 0) * 64]);
        gld16(pa + 8L * K + k0,  &lds[sl][(wid * 32 + 8) * 64]); };
    auto stA23 = [&](int s) { int sl = s % 3; long k0 = (long)s * 64;
        gld16(pa + 16L * K + k0, &lds[sl][(wid * 32 + 16) * 64]);
        gld16(pa + 24L * K + k0, &lds[sl][(wid * 32 + 24) * 64]); };
    auto stB0  = [&](int s) { int sl = s % 3; long k0 = (long)s * 64;
        gld16(pb + k0,           &lds[sl][16384 + (wid * 16 + 0) * 64]); };
    auto stB1  = [&](int s) { int sl = s % 3; long k0 = (long)s * 64;
        gld16(pb + 8L * K + k0,  &lds[sl][16384 + (wid * 16 + 8) * 64]); };

    auto stage_all = [&](int s) { stA01(s); stA23(s); stB0(s); stB1(s); };

    const int S = K >> 6;
    stage_all(0); stage_all(1);                       // 12 in flight
    asm volatile("s_waitcnt vmcnt(6)" ::: "memory");  // tile 0 landed (own)
    __builtin_amdgcn_s_barrier();                     // ...for all waves

    v8bf b0, b1;                   // B frags persist across the mh pair
    for (int s = 0; s < S; ++s) {
        const int sl = s % 3;
        const ushort* sa = &lds[sl][0];
        const ushort* sb = &lds[sl][16384];
        const bool st = (s + 2 < S);

        #pragma unroll
        for (int kh = 0; kh < 2; ++kh) {
            const int sw = ((kh * 4 + hi) ^ (fr & 7)) * 8;
            #pragma unroll
            for (int mh = 0; mh < 2; ++mh) {
                // phase: ds_reads of current tile ∥ stage-issue for s+2
                v8bf a[4];
                #pragma unroll
                for (int m = 0; m < 4; m++)
                    a[m] = *(const v8bf*)&sa[(wm * 128 + mh * 64 + m * 16 + fr) * 64 + sw];
                if (mh == 0) {
                    b0 = *(const v8bf*)&sb[(wn * 32 + fr) * 64 + sw];
                    b1 = *(const v8bf*)&sb[(wn * 32 + 16 + fr) * 64 + sw];
                }
                if (st) {
                    if (kh == 0) { if (mh == 0) stA01(s + 2); else stA23(s + 2); }
                    else         { if (mh == 0) stB0(s + 2);  else stB1(s + 2); }
                }
                __builtin_amdgcn_s_barrier();
                __builtin_amdgcn_s_setprio(1);
                #pragma unroll
                for (int m = 0; m < 4; m++) {
                    acc[mh * 4 + m][0] = __builtin_amdgcn_mfma_f32_16x16x32_bf16(a[m], b0, acc[mh * 4 + m][0], 0, 0, 0);
                    acc[mh * 4 + m][1] = __builtin_amdgcn_mfma_f32_16x16x32_bf16(a[m], b1, acc[mh * 4 + m][1], 0, 0, 0);
                }
                __builtin_amdgcn_s_setprio(0);
                if (!(kh == 1 && mh == 1))
                    __builtin_amdgcn_s_barrier();     // inter-phase barrier
            }
        }
        // tile's final barrier, fused with the counted wait: after this
        // barrier, EVERY wave's tile-(s+1) DMA has landed (outstanding here
        // = tile s+1 (6) + tile s+2 (6 if issued); vmcnt(6) drains s+1).
        if (s < S - 1) {
            if (s + 2 < S) asm volatile("s_waitcnt vmcnt(6)" ::: "memory");
            else           asm volatile("s_waitcnt vmcnt(0)" ::: "memory");
            __builtin_amdgcn_s_barrier();
        }
    }

    // epilogue: C/D layout col=lane&15, row=(lane>>4)*4+jj (m89-verified)
    const int cr  = (lane >> 4) * 4;
    const int cc2 = lane & 15;
    #pragma unroll
    for (int m = 0; m < 8; m++)
        for (int n = 0; n < 2; n++) {
            long row = brow + wm * 128 + m * 16 + cr;
            long col = bcol + wn * 32 + n * 16 + cc2;
            for (int jj = 0; jj < 4; jj++)
                C[(row + jj) * (long)N + col] = f2bf(acc[m][n][jj]);
        }
}

// ---------------------------------------------------------------------------
// Fallback GEMM (round-4 proven): used for GEMM2 (K=64, too shallow to pipe).
// ---------------------------------------------------------------------------
#define BM 128
#define BN 128
#define BKK 32

template<int RELU>
__global__ __launch_bounds__(256)
void gemm_bt(const ushort* __restrict__ A, const ushort* __restrict__ B,
             ushort* __restrict__ C, int M, int N, int K)
{
    __shared__ ushort sA[BM * BKK];
    __shared__ ushort sB[BN * BKK];
    const int t    = threadIdx.x;
    const int lane = t & 63;
    const int wid  = t >> 6;

    int wg = blockIdx.y * gridDim.x + blockIdx.x;
    const int chunk = (gridDim.x * gridDim.y) >> 3;
    wg = (wg & 7) * chunk + (wg >> 3);
    const int bx = wg % gridDim.x;
    const int by = wg / gridDim.x;

    const int wr   = (wid >> 1) * 64;
    const int wc   = (wid & 1) * 64;
    const long brow = (long)by * BM;
    const long bcol = (long)bx * BN;

    const int ls = lane >> 2;
    const int lc = (lane & 3) * 8;
    const int srow = wid * 32;
    const ushort* pa = A + (brow + srow + ls) * (long)K + lc;
    const ushort* pb = B + (bcol + srow + ls) * (long)K + lc;
    ushort* la0 = &sA[srow * BKK];
    ushort* la1 = &sA[(srow + 16) * BKK];
    ushort* lb0 = &sB[srow * BKK];
    ushort* lb1 = &sB[(srow + 16) * BKK];

    f32x4 acc[4][4];
    const f32x4 z = {0.f, 0.f, 0.f, 0.f};
    for (int m = 0; m < 4; m++)
        for (int n = 0; n < 4; n++) acc[m][n] = z;

    const int fr = lane & 15;
    const int fk = (lane >> 4) * 8;

    for (int k0 = 0; k0 < K; k0 += BKK) {
        __syncthreads();
        gld16(pa + k0,           la0);
        gld16(pa + 16L * K + k0, la1);
        gld16(pb + k0,           lb0);
        gld16(pb + 16L * K + k0, lb1);
        __syncthreads();
        v8bf a[4], b[4];
        for (int m = 0; m < 4; m++)
            a[m] = *(const v8bf*)&sA[(wr + m * 16 + fr) * BKK + fk];
        for (int n = 0; n < 4; n++)
            b[n] = *(const v8bf*)&sB[(wc + n * 16 + fr) * BKK + fk];
        for (int m = 0; m < 4; m++)
            for (int n = 0; n < 4; n++)
                acc[m][n] = __builtin_amdgcn_mfma_f32_16x16x32_bf16(a[m], b[n], acc[m][n], 0, 0, 0);
    }

    const int cr  = (lane >> 4) * 4;
    const int cc2 = lane & 15;
    for (int m = 0; m < 4; m++)
        for (int n = 0; n < 4; n++) {
            long row = brow + wr + m * 16 + cr;
            long col = bcol + wc + n * 16 + cc2;
            for (int j = 0; j < 4; j++) {
                float v = acc[m][n][j];
                if (RELU) v = v > 0.f ? v : 0.f;
                C[(row + j) * (long)N + col] = f2bf(v);
            }
        }
}

// ---------------------------------------------------------------------------
// LN1: x1 = LayerNorm(x + attn)*g1 + b1 ; q = cos(x1[:, :64] + theta_ffn)
// ---------------------------------------------------------------------------
__global__ __launch_bounds__(256)
void ln1_kernel(const float* __restrict__ x, const ushort* __restrict__ attn,
                const float* __restrict__ g1, const float* __restrict__ b1,
                const float* __restrict__ theta_ffn,
                ushort* __restrict__ x1, ushort* __restrict__ q)
{
    const int row = blockIdx.x;
    const int t   = threadIdx.x;
    const long base = (long)row * 1024 + t * 4;
    float4  xu = *(const float4*)&x[base];
    ushort4 au = *(const ushort4*)&attn[base];
    float y0 = xu.x + bf2f(au.x);
    float y1 = xu.y + bf2f(au.y);
    float y2 = xu.z + bf2f(au.z);
    float y3 = xu.w + bf2f(au.w);
    float s  = y0 + y1 + y2 + y3;
    float ss = y0 * y0 + y1 * y1 + y2 * y2 + y3 * y3;
    for (int off = 32; off > 0; off >>= 1) {
        s  += __shfl_down(s, off, 64);
        ss += __shfl_down(ss, off, 64);
    }
    __shared__ float red[8];
    const int lane = t & 63, wid = t >> 6;
    if (lane == 0) { red[wid] = s; red[4 + wid] = ss; }
    __syncthreads();
    s  = red[0] + red[1] + red[2] + red[3];
    ss = red[4] + red[5] + red[6] + red[7];
    const float mu   = s * (1.0f / 1024.0f);
    const float var  = ss * (1.0f / 1024.0f) - mu * mu;
    const float rstd = rsqrtf(var + 1e-5f);
    float4 gu = *(const float4*)&g1[t * 4];
    float4 bu = *(const float4*)&b1[t * 4];
    float o0 = (y0 - mu) * rstd * gu.x + bu.x;
    float o1 = (y1 - mu) * rstd * gu.y + bu.y;
    float o2 = (y2 - mu) * rstd * gu.z + bu.z;
    float o3 = (y3 - mu) * rstd * gu.w + bu.w;
    ushort4 ou; ou.x = f2bf(o0); ou.y = f2bf(o1); ou.z = f2bf(o2); ou.w = f2bf(o3);
    *(ushort4*)&x1[base] = ou;
    if (t < 16) {
        float4 tu = *(const float4*)&theta_ffn[t * 4];
        ushort4 qu;
        qu.x = f2bf(cosf(o0 + tu.x));
        qu.y = f2bf(cosf(o1 + tu.y));
        qu.z = f2bf(cosf(o2 + tu.z));
        qu.w = f2bf(cosf(o3 + tu.w));
        *(ushort4*)&q[(long)row * 64 + t * 4] = qu;
    }
}

// ---------------------------------------------------------------------------
// LN2: out = LayerNorm(x1 + ffn)*g2 + b2   (d_out is FP32)
// ---------------------------------------------------------------------------
__global__ __launch_bounds__(256)
void ln2_kernel(const ushort* __restrict__ x1, const ushort* __restrict__ ffn,
                const float* __restrict__ g2, const float* __restrict__ b2,
                float* __restrict__ out)
{
    const int row = blockIdx.x;
    const int t   = threadIdx.x;
    const long base = (long)row * 1024 + t * 4;
    ushort4 xu = *(const ushort4*)&x1[base];
    ushort4 au = *(const ushort4*)&ffn[base];
    float y0 = bf2f(xu.x) + bf2f(au.x);
    float y1 = bf2f(xu.y) + bf2f(au.y);
    float y2 = bf2f(xu.z) + bf2f(au.z);
    float y3 = bf2f(xu.w) + bf2f(au.w);
    float s  = y0 + y1 + y2 + y3;
    float ss = y0 * y0 + y1 * y1 + y2 * y2 + y3 * y3;
    for (int off = 32; off > 0; off >>= 1) {
        s  += __shfl_down(s, off, 64);
        ss += __shfl_down(ss, off, 64);
    }
    __shared__ float red[8];
    const int lane = t & 63, wid = t >> 6;
    if (lane == 0) { red[wid] = s; red[4 + wid] = ss; }
    __syncthreads();
    s  = red[0] + red[1] + red[2] + red[3];
    ss = red[4] + red[5] + red[6] + red[7];
    const float mu   = s * (1.0f / 1024.0f);
    const float var  = ss * (1.0f / 1024.0f) - mu * mu;
    const float rstd = rsqrtf(var + 1e-5f);
    float4 gu = *(const float4*)&g2[t * 4];
    float4 bu = *(const float4*)&b2[t * 4];
    float4 ou;
    ou.x = (y0 - mu) * rstd * gu.x + bu.x;
    ou.y = (y1 - mu) * rstd * gu.y + bu.y;
    ou.z = (y2 - mu) * rstd * gu.z + bu.z;
    ou.w = (y3 - mu) * rstd * gu.w + bu.w;
    *(float4*)&out[base] = ou;
}

// ---------------------------------------------------------------------------
extern "C" void kernel_launch(void* const* d_in, const int* in_sizes, int n_in,
                              void* d_out, int out_size, void* d_ws, size_t ws_size,
                              hipStream_t stream)
{
    const int E = 1024, FFN = 4096;
    const long T = 8192;
    const long NE = T * E;

    const float* x       = (const float*)d_in[0];
    const float* th_attn = (const float*)d_in[1];
    const float* Wc      = (const float*)d_in[2];
    const float* g1      = (const float*)d_in[3];
    const float* b1      = (const float*)d_in[4];
    const float* th_ffn  = (const float*)d_in[5];
    const float* W1      = (const float*)d_in[6];
    const float* W2      = (const float*)d_in[7];
    const float* g2      = (const float*)d_in[8];
    const float* b2      = (const float*)d_in[9];
    float* out = (float*)d_out;

    ushort* ws   = (ushort*)d_ws;
    ushort* meas = ws;  ws += NE;
    ushort* attn = ws;  ws += NE;
    ushort* x1b  = ws;  ws += NE;
    ushort* q    = ws;  ws += T * 64;
    ushort* h    = ws;  ws += T * FFN;
    ushort* ffn  = ws;  ws += NE;
    ushort* wcb  = ws;  ws += (long)E * E;
    ushort* w1b  = ws;  ws += (long)FFN * 64;
    ushort* w2b  = meas;   // overlays meas (dead after GEMM1)
    if (ws_size < (size_t)((char*)ws - (char*)d_ws)) return;

    const long nWc = (long)E * E, nW1 = (long)FFN * 64, nW2 = (long)E * FFN;

    cvt_bf16_kernel<<<dim3((int)(nWc / 2048)), 256, 0, stream>>>(Wc, wcb, nWc);
    cvt_bf16_kernel<<<dim3((int)(nW1 / 2048)), 256, 0, stream>>>(W1, w1b, nW1);
    meas_kernel<<<dim3((int)(NE / 2048)), 256, 0, stream>>>(x, th_attn, meas, NE);
    // GEMM1: meas(8192x1024) @ Wc^T — phase-interleaved (S=16), grid 8x32=256 (1/CU)
    gemm_pipe8<<<dim3(E / 128, (int)(T / 256)), 512, 0, stream>>>(meas, wcb, attn, (int)T, E, E);
    cvt_bf16_kernel<<<dim3((int)(nW2 / 2048)), 256, 0, stream>>>(W2, w2b, nW2);
    ln1_kernel<<<dim3((int)T), 256, 0, stream>>>(x, attn, g1, b1, th_ffn, x1b, q);
    // GEMM2: K=64 too shallow for the pipe — round-4 kernel
    gemm_bt<1><<<dim3(FFN / BN, (int)(T / BM)), 256, 0, stream>>>(q, w1b, h, (int)T, FFN, 64);
    // GEMM3: h(8192x4096) @ W2^T — phase-interleaved (S=64), grid 8x32=256 (1/CU)
    gemm_pipe8<<<dim3(E / 128, (int)(T / 256)), 512, 0, stream>>>(h, w2b, ffn, (int)T, E, FFN);
    ln2_kernel<<<dim3((int)T), 256, 0, stream>>>(x1b, ffn, g2, b2, out);
}

// Round 11
// 152.818 us; speedup vs baseline: 1.0805x; 1.0805x over previous
//
#include <hip/hip_runtime.h>
#include <hip/hip_bf16.h>

typedef __bf16 v8bf __attribute__((ext_vector_type(8)));
typedef float f32x4 __attribute__((ext_vector_type(4)));

__device__ __forceinline__ float bf2f(ushort u) {
    union { uint i; float f; } c; c.i = ((uint)u) << 16; return c.f;
}
__device__ __forceinline__ ushort f2bf(float f) {
    union { float f; uint i; } c; c.f = f;
    uint r = c.i + 0x7fffu + ((c.i >> 16) & 1u);
    return (ushort)(r >> 16);
}

// global -> LDS direct DMA, 16B per lane. LDS dest wave-uniform base; HW
// writes base + lane*16. Global src per-lane.
__device__ __forceinline__ void gld16(const ushort* g, ushort* l) {
    __builtin_amdgcn_global_load_lds(
        (const __attribute__((address_space(1))) uint*)(uintptr_t)g,
        (__attribute__((address_space(3))) uint*)(uint)(uintptr_t)l,
        16, 0, 0);
}

// ---------------------------------------------------------------------------
// prep: one launch covering  meas = cos(x+theta)  |  Wc->bf16  |  W1->bf16.
// Ranges are 2048-elem aligned so each block sees one branch only.
// ---------------------------------------------------------------------------
__global__ __launch_bounds__(256)
void prep_kernel(const float* __restrict__ x, const float* __restrict__ theta,
                 ushort* __restrict__ meas,
                 const float* __restrict__ Wc, ushort* __restrict__ wcb,
                 const float* __restrict__ W1, ushort* __restrict__ w1b)
{
    const long NE = 8388608, nWc = 1048576;
    long i = ((long)blockIdx.x * blockDim.x + threadIdx.x) * 8;
    if (i < NE) {
        float4 a0 = *(const float4*)&x[i];
        float4 a1 = *(const float4*)&x[i + 4];
        int tb = (int)(i & 63);
        float4 t0 = *(const float4*)&theta[tb];
        float4 t1 = *(const float4*)&theta[tb + 4];
        ushort4 o0, o1;
        o0.x = f2bf(cosf(a0.x + t0.x));
        o0.y = f2bf(cosf(a0.y + t0.y));
        o0.z = f2bf(cosf(a0.z + t0.z));
        o0.w = f2bf(cosf(a0.w + t0.w));
        o1.x = f2bf(cosf(a1.x + t1.x));
        o1.y = f2bf(cosf(a1.y + t1.y));
        o1.z = f2bf(cosf(a1.z + t1.z));
        o1.w = f2bf(cosf(a1.w + t1.w));
        *(ushort4*)&meas[i]     = o0;
        *(ushort4*)&meas[i + 4] = o1;
    } else {
        const float* src; ushort* dst; long j;
        if (i < NE + nWc) { src = Wc; dst = wcb; j = i - NE; }
        else              { src = W1; dst = w1b; j = i - NE - nWc; }
        float4 a0 = *(const float4*)&src[j];
        float4 a1 = *(const float4*)&src[j + 4];
        ushort4 o0, o1;
        o0.x = f2bf(a0.x); o0.y = f2bf(a0.y); o0.z = f2bf(a0.z); o0.w = f2bf(a0.w);
        o1.x = f2bf(a1.x); o1.y = f2bf(a1.y); o1.z = f2bf(a1.z); o1.w = f2bf(a1.w);
        *(ushort4*)&dst[j]     = o0;
        *(ushort4*)&dst[j + 4] = o1;
    }
}

// ---------------------------------------------------------------------------
// fp32 -> bf16 conversion (W2, launched after GEMM1)
// ---------------------------------------------------------------------------
__global__ __launch_bounds__(256)
void cvt_bf16_kernel(const float* __restrict__ src, ushort* __restrict__ dst, long n)
{
    long i = ((long)blockIdx.x * blockDim.x + threadIdx.x) * 8;
    if (i >= n) return;
    float4 a0 = *(const float4*)&src[i];
    float4 a1 = *(const float4*)&src[i + 4];
    ushort4 o0, o1;
    o0.x = f2bf(a0.x); o0.y = f2bf(a0.y); o0.z = f2bf(a0.z); o0.w = f2bf(a0.w);
    o1.x = f2bf(a1.x); o1.y = f2bf(a1.y); o1.z = f2bf(a1.z); o1.w = f2bf(a1.w);
    *(ushort4*)&dst[i]     = o0;
    *(ushort4*)&dst[i + 4] = o1;
}

// ---------------------------------------------------------------------------
// Pipelined GEMM (r8-proven): C = relu?(A @ B^T), BM=BN=128, BK=64,
// 256 thr / 4 waves (2Mx2N, wave tile 64x64), ring of 2 LDS slots (64 KB ->
// 2 blocks/CU), counted vmcnt(8), both-sides XOR swizzle chunk^=(row&7)
// (0 conflicts, r7-verified), setprio, T1 XCD-chunked block swizzle.
// Degenerates correctly at S=1 (K=64): stage-once -> vmcnt(0) -> compute.
// Requires K%64==0, M%128==0, N%128==0, nwg%8==0.
// ---------------------------------------------------------------------------
template<int RELU>
__global__ __launch_bounds__(256)
void gemm_pipe(const ushort* __restrict__ A, const ushort* __restrict__ B,
               ushort* __restrict__ C, int M, int N, int K)
{
    // slot: A [128 rows][64 elems] at 0, B [128 rows][64] at 8192 (ushort idx)
    __shared__ ushort lds[2][16384];   // 2 x 32 KB = 64 KB

    const int t    = threadIdx.x;
    const int lane = t & 63;
    const int wid  = t >> 6;
    const int wm   = wid >> 1;     // 0..1 -> 64-row band
    const int wn   = wid & 1;      // 0..1 -> 64-col band

    int wg = blockIdx.y * gridDim.x + blockIdx.x;
    const int nwg = gridDim.x * gridDim.y;
    const int chunk = nwg >> 3;
    wg = (wg & 7) * chunk + (wg >> 3);
    const int bx = wg % gridDim.x;
    const int by = wg / gridDim.x;
    const long brow = (long)by * 128;
    const long bcol = (long)bx * 128;

    // staging: gld16 writes LDS linearly (lane -> row lane>>3, chunk lane&7).
    // Inverse swizzle on SOURCE so swizzled reads find chunk c at slot c^(r&7):
    const int lr = lane >> 3;                 // row within 8-row group (0..7)
    const int co = ((lane & 7) ^ lr) * 8;     // global k-chunk (elems)
    const ushort* pa = A + (brow + wid * 32 + lr) * (long)K + co;
    const ushort* pb = B + (bcol + wid * 32 + lr) * (long)K + co;

    f32x4 acc[4][4];
    const f32x4 z = {0.f, 0.f, 0.f, 0.f};
    for (int m = 0; m < 4; m++)
        for (int n = 0; n < 4; n++) acc[m][n] = z;

    const int fr = lane & 15;
    const int hi = lane >> 4;

    auto stage = [&](int s) {
        const int slot = s & 1;
        const long k0 = (long)s * 64;
        ushort* base = &lds[slot][0];
        #pragma unroll
        for (int g = 0; g < 4; ++g)
            gld16(pa + g * 8L * K + k0, base + (wid * 32 + g * 8) * 64);
        #pragma unroll
        for (int g = 0; g < 4; ++g)
            gld16(pb + g * 8L * K + k0, base + 8192 + (wid * 32 + g * 8) * 64);
    };

    auto compute = [&](int s) {
        const int slot = s & 1;
        const ushort* sa = &lds[slot][0];
        const ushort* sb = &lds[slot][8192];
        #pragma unroll
        for (int ks = 0; ks < 2; ++ks) {
            const int sw = ((ks * 4 + hi) ^ (fr & 7)) * 8;   // swizzled chunk
            v8bf a[4], b[4];
            #pragma unroll
            for (int m = 0; m < 4; m++)
                a[m] = *(const v8bf*)&sa[(wm * 64 + m * 16 + fr) * 64 + sw];
            #pragma unroll
            for (int n = 0; n < 4; n++)
                b[n] = *(const v8bf*)&sb[(wn * 64 + n * 16 + fr) * 64 + sw];
            __builtin_amdgcn_s_setprio(1);
            #pragma unroll
            for (int m = 0; m < 4; m++)
                #pragma unroll
                for (int n = 0; n < 4; n++)
                    acc[m][n] = __builtin_amdgcn_mfma_f32_16x16x32_bf16(a[m], b[n], acc[m][n], 0, 0, 0);
            __builtin_amdgcn_s_setprio(0);
        }
    };

    const int S = K >> 6;          // BK=64 slabs
    stage(0);                      // 8 loads in flight per wave

    for (int s = 0; s < S - 1; ++s) {
        stage(s + 1);                                    // other slot (readers of s-1 done)
        asm volatile("s_waitcnt vmcnt(8)" ::: "memory"); // slab-s loads landed; s+1 in flight
        __builtin_amdgcn_s_barrier();                    // all waves' slab-s loads landed
        compute(s);
        __builtin_amdgcn_s_barrier();                    // all reads of slot s&1 done
    }
    asm volatile("s_waitcnt vmcnt(0)" ::: "memory");
    __builtin_amdgcn_s_barrier();
    compute(S - 1);

    // epilogue: C/D layout col=lane&15, row=(lane>>4)*4+jj (m89-verified)
    const int cr  = (lane >> 4) * 4;
    const int cc2 = lane & 15;
    for (int m = 0; m < 4; m++)
        for (int n = 0; n < 4; n++) {
            long row = brow + wm * 64 + m * 16 + cr;
            long col = bcol + wn * 64 + n * 16 + cc2;
            for (int jj = 0; jj < 4; jj++) {
                float v = acc[m][n][jj];
                if (RELU) v = v > 0.f ? v : 0.f;
                C[(row + jj) * (long)N + col] = f2bf(v);
            }
        }
}

// ---------------------------------------------------------------------------
// LN1: x1 = LayerNorm(x + attn)*g1 + b1 ; q = cos(x1[:, :64] + theta_ffn)
// ---------------------------------------------------------------------------
__global__ __launch_bounds__(256)
void ln1_kernel(const float* __restrict__ x, const ushort* __restrict__ attn,
                const float* __restrict__ g1, const float* __restrict__ b1,
                const float* __restrict__ theta_ffn,
                ushort* __restrict__ x1, ushort* __restrict__ q)
{
    const int row = blockIdx.x;
    const int t   = threadIdx.x;
    const long base = (long)row * 1024 + t * 4;
    float4  xu = *(const float4*)&x[base];
    ushort4 au = *(const ushort4*)&attn[base];
    float y0 = xu.x + bf2f(au.x);
    float y1 = xu.y + bf2f(au.y);
    float y2 = xu.z + bf2f(au.z);
    float y3 = xu.w + bf2f(au.w);
    float s  = y0 + y1 + y2 + y3;
    float ss = y0 * y0 + y1 * y1 + y2 * y2 + y3 * y3;
    for (int off = 32; off > 0; off >>= 1) {
        s  += __shfl_down(s, off, 64);
        ss += __shfl_down(ss, off, 64);
    }
    __shared__ float red[8];
    const int lane = t & 63, wid = t >> 6;
    if (lane == 0) { red[wid] = s; red[4 + wid] = ss; }
    __syncthreads();
    s  = red[0] + red[1] + red[2] + red[3];
    ss = red[4] + red[5] + red[6] + red[7];
    const float mu   = s * (1.0f / 1024.0f);
    const float var  = ss * (1.0f / 1024.0f) - mu * mu;
    const float rstd = rsqrtf(var + 1e-5f);
    float4 gu = *(const float4*)&g1[t * 4];
    float4 bu = *(const float4*)&b1[t * 4];
    float o0 = (y0 - mu) * rstd * gu.x + bu.x;
    float o1 = (y1 - mu) * rstd * gu.y + bu.y;
    float o2 = (y2 - mu) * rstd * gu.z + bu.z;
    float o3 = (y3 - mu) * rstd * gu.w + bu.w;
    ushort4 ou; ou.x = f2bf(o0); ou.y = f2bf(o1); ou.z = f2bf(o2); ou.w = f2bf(o3);
    *(ushort4*)&x1[base] = ou;
    if (t < 16) {
        float4 tu = *(const float4*)&theta_ffn[t * 4];
        ushort4 qu;
        qu.x = f2bf(cosf(o0 + tu.x));
        qu.y = f2bf(cosf(o1 + tu.y));
        qu.z = f2bf(cosf(o2 + tu.z));
        qu.w = f2bf(cosf(o3 + tu.w));
        *(ushort4*)&q[(long)row * 64 + t * 4] = qu;
    }
}

// ---------------------------------------------------------------------------
// LN2: out = LayerNorm(x1 + ffn)*g2 + b2   (d_out is FP32)
// ---------------------------------------------------------------------------
__global__ __launch_bounds__(256)
void ln2_kernel(const ushort* __restrict__ x1, const ushort* __restrict__ ffn,
                const float* __restrict__ g2, const float* __restrict__ b2,
                float* __restrict__ out)
{
    const int row = blockIdx.x;
    const int t   = threadIdx.x;
    const long base = (long)row * 1024 + t * 4;
    ushort4 xu = *(const ushort4*)&x1[base];
    ushort4 au = *(const ushort4*)&ffn[base];
    float y0 = bf2f(xu.x) + bf2f(au.x);
    float y1 = bf2f(xu.y) + bf2f(au.y);
    float y2 = bf2f(xu.z) + bf2f(au.z);
    float y3 = bf2f(xu.w) + bf2f(au.w);
    float s  = y0 + y1 + y2 + y3;
    float ss = y0 * y0 + y1 * y1 + y2 * y2 + y3 * y3;
    for (int off = 32; off > 0; off >>= 1) {
        s  += __shfl_down(s, off, 64);
        ss += __shfl_down(ss, off, 64);
    }
    __shared__ float red[8];
    const int lane = t & 63, wid = t >> 6;
    if (lane == 0) { red[wid] = s; red[4 + wid] = ss; }
    __syncthreads();
    s  = red[0] + red[1] + red[2] + red[3];
    ss = red[4] + red[5] + red[6] + red[7];
    const float mu   = s * (1.0f / 1024.0f);
    const float var  = ss * (1.0f / 1024.0f) - mu * mu;
    const float rstd = rsqrtf(var + 1e-5f);
    float4 gu = *(const float4*)&g2[t * 4];
    float4 bu = *(const float4*)&b2[t * 4];
    float4 ou;
    ou.x = (y0 - mu) * rstd * gu.x + bu.x;
    ou.y = (y1 - mu) * rstd * gu.y + bu.y;
    ou.z = (y2 - mu) * rstd * gu.z + bu.z;
    ou.w = (y3 - mu) * rstd * gu.w + bu.w;
    *(float4*)&out[base] = ou;
}

// ---------------------------------------------------------------------------
extern "C" void kernel_launch(void* const* d_in, const int* in_sizes, int n_in,
                              void* d_out, int out_size, void* d_ws, size_t ws_size,
                              hipStream_t stream)
{
    const int E = 1024, FFN = 4096;
    const long T = 8192;
    const long NE = T * E;

    const float* x       = (const float*)d_in[0];
    const float* th_attn = (const float*)d_in[1];
    const float* Wc      = (const float*)d_in[2];
    const float* g1      = (const float*)d_in[3];
    const float* b1      = (const float*)d_in[4];
    const float* th_ffn  = (const float*)d_in[5];
    const float* W1      = (const float*)d_in[6];
    const float* W2      = (const float*)d_in[7];
    const float* g2      = (const float*)d_in[8];
    const float* b2      = (const float*)d_in[9];
    float* out = (float*)d_out;

    ushort* ws   = (ushort*)d_ws;
    ushort* meas = ws;  ws += NE;
    ushort* attn = ws;  ws += NE;
    ushort* x1b  = ws;  ws += NE;
    ushort* q    = ws;  ws += T * 64;
    ushort* h    = ws;  ws += T * FFN;
    ushort* ffn  = ws;  ws += NE;
    ushort* wcb  = ws;  ws += (long)E * E;
    ushort* w1b  = ws;  ws += (long)FFN * 64;
    ushort* w2b  = meas;   // overlays meas (dead after GEMM1)
    if (ws_size < (size_t)((char*)ws - (char*)d_ws)) return;

    const long nWc = (long)E * E, nW1 = (long)FFN * 64, nW2 = (long)E * FFN;

    // prep: meas + Wc->bf16 + W1->bf16 in one launch (ranges 2048-aligned)
    prep_kernel<<<dim3((int)((NE + nWc + nW1) / 2048)), 256, 0, stream>>>(
        x, th_attn, meas, Wc, wcb, W1, w1b);
    // GEMM1: meas(8192x1024) @ Wc^T — pipelined (S=16), grid 8x64=512 (2/CU)
    gemm_pipe<0><<<dim3(E / 128, (int)(T / 128)), 256, 0, stream>>>(meas, wcb, attn, (int)T, E, E);
    cvt_bf16_kernel<<<dim3((int)(nW2 / 2048)), 256, 0, stream>>>(W2, w2b, nW2);
    ln1_kernel<<<dim3((int)T), 256, 0, stream>>>(x, attn, g1, b1, th_ffn, x1b, q);
    // GEMM2: q(8192x64) @ W1^T — S=1 degenerate pipe, +ReLU, grid 32x64=2048
    gemm_pipe<1><<<dim3(FFN / 128, (int)(T / 128)), 256, 0, stream>>>(q, w1b, h, (int)T, FFN, 64);
    // GEMM3: h(8192x4096) @ W2^T — pipelined (S=64), grid 8x64=512 (2/CU)
    gemm_pipe<0><<<dim3(E / 128, (int)(T / 128)), 256, 0, stream>>>(h, w2b, ffn, (int)T, E, FFN);
    ln2_kernel<<<dim3((int)T), 256, 0, stream>>>(x1b, ffn, g2, b2, out);
}